// Round 2
// baseline (2563.948 us; speedup 1.0000x reference)
//
#include <hip/hip_runtime.h>
#include <hip/hip_cooperative_groups.h>
#include <cstdint>
#include <cstddef>

namespace cg = cooperative_groups;

typedef unsigned short u16;
typedef short s8v __attribute__((ext_vector_type(8)));
typedef float f4v __attribute__((ext_vector_type(4)));

static __device__ __forceinline__ u16 f2bf(float x) {
  union { float f; uint32_t u; } v; v.f = x;
  uint32_t r = v.u + 0x7fffu + ((v.u >> 16) & 1u);   // RNE
  return (u16)(r >> 16);
}
static __device__ __forceinline__ float sigm(float x) { return 1.0f / (1.0f + __expf(-x)); }

// ---------------- prep: bf16 conversions + emb gather + bias sum ----------------
__global__ void kPrep(const float* __restrict__ fcW, const float* __restrict__ attnW,
                      const float* __restrict__ Wih, const float* __restrict__ bih,
                      const float* __restrict__ bhh, const float* __restrict__ embW,
                      const int* __restrict__ decX,
                      u16* __restrict__ fcWb, u16* __restrict__ attnWb, u16* __restrict__ Wihb,
                      u16* __restrict__ embg, float* __restrict__ biassum) {
  const long NF = 16384000L, NA = 524288L, NW = 524288L, NE = 524288L, NB = 2048L;
  const long total = NF + NA + NW + NE + NB;
  for (long i = (long)blockIdx.x * blockDim.x + threadIdx.x; i < total;
       i += (long)gridDim.x * blockDim.x) {
    if (i < NF) {
      fcWb[i] = f2bf(fcW[i]);
    } else if (i < NF + NA) {
      long k = i - NF; attnWb[k] = f2bf(attnW[k]);
    } else if (i < NF + NA + NW) {
      long k = i - NF - NA; Wihb[k] = f2bf(Wih[k]);
    } else if (i < NF + NA + NW + NE) {
      long k = i - NF - NA - NW;
      int row = (int)(k >> 8), e = (int)(k & 255);   // row = t*32+b
      int t = row >> 5, b = row & 31;
      int x = decX[b * 64 + t];
      embg[k] = f2bf(embW[(long)x * 256 + e]);       // emb_W[0] is all-zero => padding ok
    } else {
      long k = i - NF - NA - NW - NE;
      biassum[k] = bih[k] + bhh[k];
    }
  }
}

// ---------------- templated bf16 MFMA GEMM: C[M,N] = A[M,K] * B[N,K]^T + bias ----------------
template <int ACT, int OUTBF>
__global__ __launch_bounds__(256) void kGemm(const u16* __restrict__ A, const u16* __restrict__ Bm,
                                             const float* __restrict__ bias,
                                             float* __restrict__ Cf, u16* __restrict__ Cb,
                                             int N, int K) {
  __shared__ u16 lA[8 * 64 * 8];
  __shared__ u16 lB[8 * 64 * 8];
  const int tid = threadIdx.x;
  const int m0 = blockIdx.x * 128, n0 = blockIdx.y * 128;
  const int lane = tid & 63, wid = tid >> 6;
  const int wm = wid >> 1, wn = wid & 1;
  f4v acc[4][4] = {};
  const int nkt = K >> 5;
  for (int kt = 0; kt < nkt; ++kt) {
    const int k0 = kt << 5;
#pragma unroll
    for (int i = 0; i < 2; ++i) {
      int u = i * 256 + tid;
      int m = u >> 2, q = u & 3;
      uint4 va = *(const uint4*)(A + (size_t)(m0 + m) * K + k0 + q * 8);
      *(uint4*)&lA[(((m >> 4) * 64) + q * 16 + (m & 15)) * 8] = va;
      uint4 vb = *(const uint4*)(Bm + (size_t)(n0 + m) * K + k0 + q * 8);
      *(uint4*)&lB[(((m >> 4) * 64) + q * 16 + (m & 15)) * 8] = vb;
    }
    __syncthreads();
    s8v af[4], bfr[4];
#pragma unroll
    for (int i = 0; i < 4; ++i) af[i] = *(const s8v*)&lA[((wm * 4 + i) * 64 + lane) * 8];
#pragma unroll
    for (int j = 0; j < 4; ++j) bfr[j] = *(const s8v*)&lB[((wn * 4 + j) * 64 + lane) * 8];
#pragma unroll
    for (int i = 0; i < 4; ++i)
#pragma unroll
      for (int j = 0; j < 4; ++j)
        acc[i][j] = __builtin_amdgcn_mfma_f32_16x16x32_bf16(af[i], bfr[j], acc[i][j], 0, 0, 0);
    __syncthreads();
  }
  const int rq = lane >> 4, cl = lane & 15;
#pragma unroll
  for (int j = 0; j < 4; ++j) {
    int col = n0 + wn * 64 + j * 16 + cl;
    float bv = bias[col];
#pragma unroll
    for (int i = 0; i < 4; ++i) {
      int rowb = m0 + wm * 64 + i * 16 + rq * 4;
      f4v v = acc[i][j];
#pragma unroll
      for (int r = 0; r < 4; ++r) {
        float x = v[r] + bv;
        if (ACT) x = tanhf(x);
        size_t off = (size_t)(rowb + r) * N + col;
        if (OUTBF) Cb[off] = f2bf(x); else Cf[off] = x;
      }
    }
  }
}

// ---------------- persistent cooperative LSTM: whole recurrence in ONE kernel ----------------
// 256 blocks (1/CU) x 256 threads. Block bx owns h-columns j0=bx*2 (=> 8 gate rows of Whh),
// which live in REGISTERS for all 64 steps. grid.sync() is the per-step barrier.
// Thread (bg=tid>>5, ks=tid&31). After the fold-reduce, lane ks holds the gate-pre for
// output index a=ks: bb=ks>>3 (b=bg*4+bb), r=ks&7 (gate=r>>1, col j0+(r&1)).
// Cell state c stays in the owning lane's register for the whole recurrence.
__global__ __launch_bounds__(256, 1) void kLSTMc(const float* __restrict__ Gpre,
                                                 const float* __restrict__ Whh,
                                                 const float* __restrict__ h0,
                                                 const float* __restrict__ c0,
                                                 float* __restrict__ Hall,
                                                 float* __restrict__ hx,
                                                 float* __restrict__ cx) {
  cg::grid_group grid = cg::this_grid();
  const int tid = threadIdx.x;
  const int j0 = blockIdx.x * 2;
  const int bg = tid >> 5, ks = tid & 31;

  // Stage Whh slice into registers: Wr[r][c] = Whh[row(r)][ (ks+32c)*4 .. +3 ]
  float4 Wr[8][4];
#pragma unroll
  for (int r = 0; r < 8; ++r) {
    const int row = (r >> 1) * 512 + j0 + (r & 1);
    const float4* wp = (const float4*)(Whh + (size_t)row * 512);
#pragma unroll
    for (int c = 0; c < 4; ++c) Wr[r][c] = wp[ks + 32 * c];
  }

  const int bb_o = ks >> 3, r_o = ks & 7;
  const int b_o = bg * 4 + bb_o;
  const int gate_o = r_o >> 1;
  const int j_o = j0 + (r_o & 1);
  const bool cellLane = (r_o < 2);
  float creg = cellLane ? c0[b_o * 512 + j_o] : 0.f;

  const float* hsrc = h0;
  for (int t = 0; t < 64; ++t) {
    // prefetch this lane's gate-pre (independent of h) early
    float gpv = Gpre[((size_t)t * 32 + b_o) * 2048 + (size_t)gate_o * 512 + j_o];

    float acc[32];
#pragma unroll
    for (int a = 0; a < 32; ++a) acc[a] = 0.f;
#pragma unroll
    for (int c = 0; c < 4; ++c) {
      float4 h4[4];
#pragma unroll
      for (int bb = 0; bb < 4; ++bb)
        h4[bb] = *(const float4*)&hsrc[(bg * 4 + bb) * 512 + (ks + 32 * c) * 4];
#pragma unroll
      for (int bb = 0; bb < 4; ++bb)
#pragma unroll
        for (int r = 0; r < 8; ++r) {
          float4 w = Wr[r][c], h = h4[bb];
          acc[bb * 8 + r] += w.x * h.x + w.y * h.y + w.z * h.z + w.w * h.w;
        }
    }

    // fold-reduce: 32 partials across 32 lanes -> lane ks ends with total for acc[ks].
    // Indices are compile-time; lane-dependent choice is by VALUE (cndmask), not index.
#define FOLD_STAGE(OFF, NN)                                        \
    {                                                              \
      const bool hi = (ks & OFF) != 0;                             \
      _Pragma("unroll")                                            \
      for (int i = 0; i < NN; ++i) {                               \
        float keepv = hi ? acc[i + NN] : acc[i];                   \
        float sendv = hi ? acc[i] : acc[i + NN];                   \
        acc[i] = keepv + __shfl_xor(sendv, OFF, 64);               \
      }                                                            \
    }
    FOLD_STAGE(16, 16)
    FOLD_STAGE(8, 8)
    FOLD_STAGE(4, 4)
    FOLD_STAGE(2, 2)
    FOLD_STAGE(1, 1)
#undef FOLD_STAGE

    // per-lane activation (i,f,o -> sigmoid; g -> tanh), fully parallel
    float pre = acc[0] + gpv;
    float v = (gate_o == 2) ? tanhf(pre) : sigm(pre);
    // gather f,g,o into the i-lanes (r_o in {0,1}); octet-local XORs
    float fv = __shfl_xor(v, 2, 64);
    float gv = __shfl_xor(v, 4, 64);
    float ov = __shfl_xor(v, 6, 64);
    float* hdst = Hall + (size_t)t * 16384;
    if (cellLane) {
      creg = fv * creg + v * gv;
      float hv = ov * tanhf(creg);
      hdst[b_o * 512 + j_o] = hv;
      if (t == 63) { hx[b_o * 512 + j_o] = hv; cx[b_o * 512 + j_o] = creg; }
    }
    hsrc = hdst;
    if (t < 63) grid.sync();
  }
}

// ---------------- attention: scores -> softmax -> context; emit CAT=[h|c_t] in bf16 ----------
__global__ __launch_bounds__(256) void kAttn(const float* __restrict__ Hall, const float* __restrict__ enc,
                                             u16* __restrict__ CAT) {
  const int bx = blockIdx.x;
  const int b = bx >> 3, tg = bx & 7;     // 8 timesteps per block
  const int tid = threadIdx.x;
  __shared__ float sh[8][516];
  __shared__ float sa[8][132];
  __shared__ float red[8][32];
  for (int tt = 0; tt < 8; ++tt) {
    int t = tg * 8 + tt;
    const float* hr = Hall + ((size_t)t * 32 + b) * 512;
    u16* cr = CAT + ((size_t)(b * 64 + t)) * 1024;
    for (int k = tid; k < 512; k += 256) { float v = hr[k]; sh[tt][k] = v; cr[k] = f2bf(v); }
  }
  __syncthreads();
  {  // scores: thread = (t_local = tid&7, e_base = tid>>3)
    const int tl = tid & 7, eb = tid >> 3;
#pragma unroll
    for (int u = 0; u < 4; ++u) {
      int e = eb + u * 32;
      const float* er = enc + ((size_t)b * 128 + e) * 512;
      float a = 0.f;
      for (int k = 0; k < 512; k += 4) {
        float4 ev = *(const float4*)&er[k];
        float4 hv = *(const float4*)&sh[tl][k];
        a += ev.x * hv.x + ev.y * hv.y + ev.z * hv.z + ev.w * hv.w;
      }
      sa[tl][e] = a;
    }
  }
  __syncthreads();
  {  // softmax over 128 per t: thread = (g = tid>>5, l = tid&31)
    const int g = tid >> 5, l = tid & 31;
    float mx = -1e30f;
#pragma unroll
    for (int u = 0; u < 4; ++u) mx = fmaxf(mx, sa[g][l + u * 32]);
    red[g][l] = mx;
    __syncthreads();
    if (l == 0) {
      float m2 = -1e30f;
      for (int i = 0; i < 32; ++i) m2 = fmaxf(m2, red[g][i]);
      sa[g][128] = m2;
    }
    __syncthreads();
    float m2 = sa[g][128];
    float s = 0.f;
#pragma unroll
    for (int u = 0; u < 4; ++u) { int e = l + u * 32; float p = __expf(sa[g][e] - m2); sa[g][e] = p; s += p; }
    red[g][l] = s;
    __syncthreads();
    if (l == 0) {
      float s2 = 0.f;
      for (int i = 0; i < 32; ++i) s2 += red[g][i];
      sa[g][129] = 1.0f / s2;
    }
    __syncthreads();
    float inv = sa[g][129];
#pragma unroll
    for (int u = 0; u < 4; ++u) sa[g][l + u * 32] *= inv;
  }
  __syncthreads();
  {  // context: thread covers cols 2*tid, 2*tid+1 for all 8 t
    float a0[8], a1[8];
#pragma unroll
    for (int tt = 0; tt < 8; ++tt) { a0[tt] = 0.f; a1[tt] = 0.f; }
    const float* eb2 = enc + (size_t)b * 128 * 512 + tid * 2;
    for (int e = 0; e < 128; ++e) {
      float2 v = *(const float2*)&eb2[(size_t)e * 512];
#pragma unroll
      for (int tt = 0; tt < 8; ++tt) { float a = sa[tt][e]; a0[tt] += a * v.x; a1[tt] += a * v.y; }
    }
#pragma unroll
    for (int tt = 0; tt < 8; ++tt) {
      int t = tg * 8 + tt;
      u16* cr = CAT + ((size_t)(b * 64 + t)) * 1024 + 512;
      cr[tid * 2] = f2bf(a0[tt]); cr[tid * 2 + 1] = f2bf(a1[tt]);
    }
  }
}

// ---------------- launcher ----------------
extern "C" void kernel_launch(void* const* d_in, const int* in_sizes, int n_in,
                              void* d_out, int out_size, void* d_ws, size_t ws_size,
                              hipStream_t stream) {
  const int*   decX  = (const int*)d_in[0];
  const float* enc   = (const float*)d_in[1];
  const float* h0    = (const float*)d_in[2];
  const float* c0    = (const float*)d_in[3];
  const float* embW  = (const float*)d_in[4];
  const float* Wih   = (const float*)d_in[5];
  const float* Whh   = (const float*)d_in[6];
  const float* bih   = (const float*)d_in[7];
  const float* bhh   = (const float*)d_in[8];
  const float* attnW = (const float*)d_in[9];
  const float* attnb = (const float*)d_in[10];
  const float* fcW   = (const float*)d_in[11];
  const float* fcb   = (const float*)d_in[12];
  float* out = (float*)d_out;

  char* ws = (char*)d_ws;
  u16*   fcWb    = (u16*)(ws);                    // 32,768,000 B
  u16*   attnWb  = (u16*)(ws + 32768000);         //  1,048,576 B
  u16*   Wihb    = (u16*)(ws + 33816576);         //  1,048,576 B
  u16*   embg    = (u16*)(ws + 34865152);         //  1,048,576 B (dead after GEMM#1)
  float* biassum = (float*)(ws + 35913728);       //      8,192 B
  float* Gpre    = (float*)(ws + 35921920);       // 16,777,216 B
  float* Hall    = (float*)(ws + 52699136);       //  4,194,304 B
  u16*   CAT     = (u16*)(ws + 56893440);         //  4,194,304 B
  u16*   OUTb    = (u16*)(ws + 61087744);         //  2,097,152 B  (total ~63.2 MB)

  hipLaunchKernelGGL(kPrep, dim3(4096), dim3(256), 0, stream,
                     fcW, attnW, Wih, bih, bhh, embW, decX, fcWb, attnWb, Wihb, embg, biassum);
  // G_pre[t*32+b][2048] = embg @ Wih^T + (b_ih+b_hh)
  hipLaunchKernelGGL((kGemm<0, 0>), dim3(16, 16), dim3(256), 0, stream,
                     embg, Wihb, biassum, Gpre, (u16*)nullptr, 2048, 256);
  // LSTM recurrence: single persistent cooperative kernel, grid.sync() per step.
  {
    float* hx = out + 65536000L;             // final h
    float* cx = out + 65536000L + 16384L;    // final c
    const float* gpreA = Gpre; const float* whhA = Whh;
    const float* h0A = h0;     const float* c0A = c0;
    float* hallA = Hall;
    void* args[] = {(void*)&gpreA, (void*)&whhA, (void*)&h0A, (void*)&c0A,
                    (void*)&hallA, (void*)&hx, (void*)&cx};
    hipLaunchCooperativeKernel((void*)kLSTMc, dim3(256), dim3(256), args, 0, stream);
  }
  hipLaunchKernelGGL(kAttn, dim3(256), dim3(256), 0, stream, Hall, enc, CAT);
  // OUT[m][512] = tanh(CAT @ attnW^T + attn_b), bf16
  hipLaunchKernelGGL((kGemm<1, 1>), dim3(16, 4), dim3(256), 0, stream,
                     CAT, attnWb, attnb, (float*)nullptr, OUTb, 512, 1024);
  // logits[m][32000] = OUT @ fcW^T + fc_b  (m = b*64+t => contiguous [B,T,V] output)
  hipLaunchKernelGGL((kGemm<0, 0>), dim3(16, 250), dim3(256), 0, stream,
                     OUTb, fcWb, fcb, out, (u16*)nullptr, 32000, 512);
}

// Round 3
// 1027.234 us; speedup vs baseline: 2.4960x; 2.4960x over previous
//
#include <hip/hip_runtime.h>
#include <cstdint>
#include <cstddef>

typedef unsigned short u16;
typedef short s8v __attribute__((ext_vector_type(8)));
typedef float f4v __attribute__((ext_vector_type(4)));

static __device__ __forceinline__ u16 f2bf(float x) {
  union { float f; uint32_t u; } v; v.f = x;
  uint32_t r = v.u + 0x7fffu + ((v.u >> 16) & 1u);   // RNE
  return (u16)(r >> 16);
}
static __device__ __forceinline__ float sigm(float x) { return 1.0f / (1.0f + __expf(-x)); }

// ---------------- prep: bf16 conversions + emb gather + bias sum + sync-zero ----------------
__global__ void kPrep(const float* __restrict__ fcW, const float* __restrict__ attnW,
                      const float* __restrict__ Wih, const float* __restrict__ bih,
                      const float* __restrict__ bhh, const float* __restrict__ embW,
                      const int* __restrict__ decX,
                      u16* __restrict__ fcWb, u16* __restrict__ attnWb, u16* __restrict__ Wihb,
                      u16* __restrict__ embg, float* __restrict__ biassum,
                      int* __restrict__ syncp) {
  const long NF = 16384000L, NA = 524288L, NW = 524288L, NE = 524288L, NB = 2048L, NS = 1024L;
  const long total = NF + NA + NW + NE + NB + NS;
  for (long i = (long)blockIdx.x * blockDim.x + threadIdx.x; i < total;
       i += (long)gridDim.x * blockDim.x) {
    if (i < NF) {
      fcWb[i] = f2bf(fcW[i]);
    } else if (i < NF + NA) {
      long k = i - NF; attnWb[k] = f2bf(attnW[k]);
    } else if (i < NF + NA + NW) {
      long k = i - NF - NA; Wihb[k] = f2bf(Wih[k]);
    } else if (i < NF + NA + NW + NE) {
      long k = i - NF - NA - NW;
      int row = (int)(k >> 8), e = (int)(k & 255);   // row = t*32+b
      int t = row >> 5, b = row & 31;
      int x = decX[b * 64 + t];
      embg[k] = f2bf(embW[(long)x * 256 + e]);       // emb_W[0] is all-zero => padding ok
    } else if (i < NF + NA + NW + NE + NB) {
      long k = i - NF - NA - NW - NE;
      biassum[k] = bih[k] + bhh[k];
    } else {
      long k = i - NF - NA - NW - NE - NB;
      syncp[k] = 0;                                  // barrier/enroll counters (ws is poisoned)
    }
  }
}

// ---------------- templated bf16 MFMA GEMM: C[M,N] = A[M,K] * B[N,K]^T + bias ----------------
template <int ACT, int OUTBF>
__global__ __launch_bounds__(256) void kGemm(const u16* __restrict__ A, const u16* __restrict__ Bm,
                                             const float* __restrict__ bias,
                                             float* __restrict__ Cf, u16* __restrict__ Cb,
                                             int N, int K) {
  __shared__ u16 lA[8 * 64 * 8];
  __shared__ u16 lB[8 * 64 * 8];
  const int tid = threadIdx.x;
  const int m0 = blockIdx.x * 128, n0 = blockIdx.y * 128;
  const int lane = tid & 63, wid = tid >> 6;
  const int wm = wid >> 1, wn = wid & 1;
  f4v acc[4][4] = {};
  const int nkt = K >> 5;
  for (int kt = 0; kt < nkt; ++kt) {
    const int k0 = kt << 5;
#pragma unroll
    for (int i = 0; i < 2; ++i) {
      int u = i * 256 + tid;
      int m = u >> 2, q = u & 3;
      uint4 va = *(const uint4*)(A + (size_t)(m0 + m) * K + k0 + q * 8);
      *(uint4*)&lA[(((m >> 4) * 64) + q * 16 + (m & 15)) * 8] = va;
      uint4 vb = *(const uint4*)(Bm + (size_t)(n0 + m) * K + k0 + q * 8);
      *(uint4*)&lB[(((m >> 4) * 64) + q * 16 + (m & 15)) * 8] = vb;
    }
    __syncthreads();
    s8v af[4], bfr[4];
#pragma unroll
    for (int i = 0; i < 4; ++i) af[i] = *(const s8v*)&lA[((wm * 4 + i) * 64 + lane) * 8];
#pragma unroll
    for (int j = 0; j < 4; ++j) bfr[j] = *(const s8v*)&lB[((wn * 4 + j) * 64 + lane) * 8];
#pragma unroll
    for (int i = 0; i < 4; ++i)
#pragma unroll
      for (int j = 0; j < 4; ++j)
        acc[i][j] = __builtin_amdgcn_mfma_f32_16x16x32_bf16(af[i], bfr[j], acc[i][j], 0, 0, 0);
    __syncthreads();
  }
  const int rq = lane >> 4, cl = lane & 15;
#pragma unroll
  for (int j = 0; j < 4; ++j) {
    int col = n0 + wn * 64 + j * 16 + cl;
    float bv = bias[col];
#pragma unroll
    for (int i = 0; i < 4; ++i) {
      int rowb = m0 + wm * 64 + i * 16 + rq * 4;
      f4v v = acc[i][j];
#pragma unroll
      for (int r = 0; r < 4; ++r) {
        float x = v[r] + bv;
        if (ACT) x = tanhf(x);
        size_t off = (size_t)(rowb + r) * N + col;
        if (OUTBF) Cb[off] = f2bf(x); else Cf[off] = x;
      }
    }
  }
}

// ---------------- XCD-local persistent LSTM ----------------
// 256 cooperative blocks x 256 threads. 140KB static LDS forces 1 block/CU (pigeonhole:
// 2 blocks would need 280KB > 160KB), so the 256 co-resident blocks occupy all 256 CUs =>
// EXACTLY 32 blocks per XCD by physical capacity. XCD x owns batches b0=4x..4x+3: the
// entire recurrence for those batches stays inside one XCD's L2; NO cross-XCD sync ever.
// Block rank (within XCD, via atomicAdd enroll) owns 16 h-cols j0=rank*16 (= 64 Whh rows),
// staged in LDS ONCE for all 64 steps. Thread (jj,g,bb) = one output, full-K dot (512 FMA),
// no cross-lane reduce; gates combine via intra-wave shfl_xor (g lives in tid bits 2..3).
// Per-XCD barrier: monotonic counter in ws, arrive(relaxed)+spin(acquire), L2-local.
#define WLDS_H 33024   /* 64 rows * 516 floats */
__global__ __launch_bounds__(256, 1) void kLSTM2(const float* __restrict__ Gpre,
                                                 const float* __restrict__ Whh,
                                                 const float* __restrict__ h0,
                                                 const float* __restrict__ c0,
                                                 float* __restrict__ Hall,
                                                 float* __restrict__ hx,
                                                 float* __restrict__ cx,
                                                 int* __restrict__ syncp) {
  __shared__ float Wl[WLDS_H + 4 * 516];   // 140,352 B: W slice + h stage (>80KB => 1 block/CU)
  __shared__ int srank;
  const int tid = threadIdx.x;

  int xcc;
  asm volatile("s_getreg_b32 %0, hwreg(HW_REG_XCC_ID)" : "=s"(xcc));
  xcc &= 7;
  if (tid == 0) srank = atomicAdd(&syncp[xcc * 64], 1);   // enroll: rank within XCD
  __syncthreads();
  const int rank = srank & 31;
  const int j0 = rank * 16;          // 16 h-columns owned by this block
  const int b0 = xcc * 4;            // 4 batches owned by this XCD
  int* cnt = &syncp[(8 + xcc) * 64]; // per-XCD barrier counter (own 256B line)

  // Stage Whh slice into LDS once: LDS row lr = g + 4*jj  <-  Whh row g*512 + j0 + jj.
  // (gate-interleaved placement => a wave's 16 distinct rows are consecutive lr => with
  //  stride 516 floats the ds_read_b128 pattern is 2-way bank aliasing = free.)
#pragma unroll
  for (int it = 0; it < 32; ++it) {
    int idx = it * 256 + tid;        // 0..8191 float4 chunks
    int lr = idx >> 7, k4 = idx & 127;
    int gg = lr & 3, jj2 = lr >> 2;
    int grow = gg * 512 + j0 + jj2;
    float4 v = *(const float4*)&Whh[(size_t)grow * 512 + k4 * 4];
    *(float4*)&Wl[lr * 516 + k4 * 4] = v;
  }

  const int jj = tid >> 4;           // 0..15 column within block
  const int g  = (tid >> 2) & 3;     // gate (i,f,g,o) -- lane bits 2..3
  const int bb = tid & 3;            // batch within XCD
  const int b  = b0 + bb;
  const int j  = j0 + jj;
  const float* wrow = &Wl[(g + 4 * jj) * 516];
  const float* hrow = &Wl[WLDS_H + bb * 516];
  float creg = (g == 0) ? c0[b * 512 + j] : 0.f;

  const float* hsrc = h0;
  __syncthreads();                   // W-LDS ready

  for (int t = 0; t < 64; ++t) {
    // gate-pre from x@Wih^T (+bias), independent of h -> issue early
    float gpv = Gpre[((size_t)t * 32 + b) * 2048 + (size_t)g * 512 + j];

    // stage h_{t-1} for our 4 batches (2KB each) into LDS; addresses are fresh per t
#pragma unroll
    for (int it = 0; it < 2; ++it) {
      int idx = it * 256 + tid;      // 0..511 float4 chunks
      int hb = idx >> 7, k4 = idx & 127;
      float4 v = *(const float4*)&hsrc[(b0 + hb) * 512 + k4 * 4];
      *(float4*)&Wl[WLDS_H + hb * 516 + k4 * 4] = v;
    }
    __syncthreads();

    // full-K dot: 512 FMA/thread, W and h both from LDS (conflict-free)
    float4 a4 = {0.f, 0.f, 0.f, 0.f};
#pragma unroll 8
    for (int k4 = 0; k4 < 128; ++k4) {
      float4 w = *(const float4*)&wrow[k4 * 4];
      float4 h = *(const float4*)&hrow[k4 * 4];
      a4.x += w.x * h.x; a4.y += w.y * h.y; a4.z += w.z * h.z; a4.w += w.w * h.w;
    }
    float pre = (a4.x + a4.z) + (a4.y + a4.w) + gpv;

    // activations: one per lane, then gather f,g,o into the i-lanes (xor flips gate bits)
    float v = (g == 2) ? tanhf(pre) : sigm(pre);
    float fv = __shfl_xor(v, 4, 64);
    float gv = __shfl_xor(v, 8, 64);
    float ov = __shfl_xor(v, 12, 64);
    float* hdst = Hall + (size_t)t * 16384;
    if (g == 0) {
      creg = fv * creg + v * gv;               // v = i-gate
      float hv = ov * tanhf(creg);
      hdst[b * 512 + j] = hv;
      if (t == 63) { hx[b * 512 + j] = hv; cx[b * 512 + j] = creg; }
    }
    __syncthreads();                 // drains vmcnt: h stores of ALL waves are in L2

    if (t < 63) {
      if (tid == 0) {
        __hip_atomic_fetch_add(cnt, 1, __ATOMIC_RELAXED, __HIP_MEMORY_SCOPE_AGENT);
        const int target = 32 * (t + 1);
        while (__hip_atomic_load(cnt, __ATOMIC_ACQUIRE, __HIP_MEMORY_SCOPE_AGENT) < target)
          __builtin_amdgcn_s_sleep(1);
      }
      __syncthreads();               // whole block held until XCD barrier passes
    }
    hsrc = hdst;
  }
}

// ---------------- attention: scores -> softmax -> context; emit CAT=[h|c_t] in bf16 ----------
__global__ __launch_bounds__(256) void kAttn(const float* __restrict__ Hall, const float* __restrict__ enc,
                                             u16* __restrict__ CAT) {
  const int bx = blockIdx.x;
  const int b = bx >> 3, tg = bx & 7;     // 8 timesteps per block
  const int tid = threadIdx.x;
  __shared__ float sh[8][516];
  __shared__ float sa[8][132];
  __shared__ float red[8][32];
  for (int tt = 0; tt < 8; ++tt) {
    int t = tg * 8 + tt;
    const float* hr = Hall + ((size_t)t * 32 + b) * 512;
    u16* cr = CAT + ((size_t)(b * 64 + t)) * 1024;
    for (int k = tid; k < 512; k += 256) { float v = hr[k]; sh[tt][k] = v; cr[k] = f2bf(v); }
  }
  __syncthreads();
  {  // scores: thread = (t_local = tid&7, e_base = tid>>3)
    const int tl = tid & 7, eb = tid >> 3;
#pragma unroll
    for (int u = 0; u < 4; ++u) {
      int e = eb + u * 32;
      const float* er = enc + ((size_t)b * 128 + e) * 512;
      float a = 0.f;
      for (int k = 0; k < 512; k += 4) {
        float4 ev = *(const float4*)&er[k];
        float4 hv = *(const float4*)&sh[tl][k];
        a += ev.x * hv.x + ev.y * hv.y + ev.z * hv.z + ev.w * hv.w;
      }
      sa[tl][e] = a;
    }
  }
  __syncthreads();
  {  // softmax over 128 per t
    const int g = tid >> 5, l = tid & 31;
    float mx = -1e30f;
#pragma unroll
    for (int u = 0; u < 4; ++u) mx = fmaxf(mx, sa[g][l + u * 32]);
    red[g][l] = mx;
    __syncthreads();
    if (l == 0) {
      float m2 = -1e30f;
      for (int i = 0; i < 32; ++i) m2 = fmaxf(m2, red[g][i]);
      sa[g][128] = m2;
    }
    __syncthreads();
    float m2 = sa[g][128];
    float s = 0.f;
#pragma unroll
    for (int u = 0; u < 4; ++u) { int e = l + u * 32; float p = __expf(sa[g][e] - m2); sa[g][e] = p; s += p; }
    red[g][l] = s;
    __syncthreads();
    if (l == 0) {
      float s2 = 0.f;
      for (int i = 0; i < 32; ++i) s2 += red[g][i];
      sa[g][129] = 1.0f / s2;
    }
    __syncthreads();
    float inv = sa[g][129];
#pragma unroll
    for (int u = 0; u < 4; ++u) sa[g][l + u * 32] *= inv;
  }
  __syncthreads();
  {  // context: thread covers cols 2*tid, 2*tid+1 for all 8 t
    float a0[8], a1[8];
#pragma unroll
    for (int tt = 0; tt < 8; ++tt) { a0[tt] = 0.f; a1[tt] = 0.f; }
    const float* eb2 = enc + (size_t)b * 128 * 512 + tid * 2;
    for (int e = 0; e < 128; ++e) {
      float2 v = *(const float2*)&eb2[(size_t)e * 512];
#pragma unroll
      for (int tt = 0; tt < 8; ++tt) { float a = sa[tt][e]; a0[tt] += a * v.x; a1[tt] += a * v.y; }
    }
#pragma unroll
    for (int tt = 0; tt < 8; ++tt) {
      int t = tg * 8 + tt;
      u16* cr = CAT + ((size_t)(b * 64 + t)) * 1024 + 512;
      cr[tid * 2] = f2bf(a0[tt]); cr[tid * 2 + 1] = f2bf(a1[tt]);
    }
  }
}

// ---------------- launcher ----------------
extern "C" void kernel_launch(void* const* d_in, const int* in_sizes, int n_in,
                              void* d_out, int out_size, void* d_ws, size_t ws_size,
                              hipStream_t stream) {
  const int*   decX  = (const int*)d_in[0];
  const float* enc   = (const float*)d_in[1];
  const float* h0    = (const float*)d_in[2];
  const float* c0    = (const float*)d_in[3];
  const float* embW  = (const float*)d_in[4];
  const float* Wih   = (const float*)d_in[5];
  const float* Whh   = (const float*)d_in[6];
  const float* bih   = (const float*)d_in[7];
  const float* bhh   = (const float*)d_in[8];
  const float* attnW = (const float*)d_in[9];
  const float* attnb = (const float*)d_in[10];
  const float* fcW   = (const float*)d_in[11];
  const float* fcb   = (const float*)d_in[12];
  float* out = (float*)d_out;

  char* ws = (char*)d_ws;
  u16*   fcWb    = (u16*)(ws);                    // 32,768,000 B
  u16*   attnWb  = (u16*)(ws + 32768000);         //  1,048,576 B
  u16*   Wihb    = (u16*)(ws + 33816576);         //  1,048,576 B
  u16*   embg    = (u16*)(ws + 34865152);         //  1,048,576 B
  float* biassum = (float*)(ws + 35913728);       //      8,192 B
  float* Gpre    = (float*)(ws + 35921920);       // 16,777,216 B
  float* Hall    = (float*)(ws + 52699136);       //  4,194,304 B
  u16*   CAT     = (u16*)(ws + 56893440);         //  4,194,304 B
  u16*   OUTb    = (u16*)(ws + 61087744);         //  2,097,152 B
  int*   syncp   = (int*)(ws + 63184896);         //      4,096 B  (total ~63.2 MB)

  hipLaunchKernelGGL(kPrep, dim3(4096), dim3(256), 0, stream,
                     fcW, attnW, Wih, bih, bhh, embW, decX, fcWb, attnWb, Wihb, embg, biassum,
                     syncp);
  // G_pre[t*32+b][2048] = embg @ Wih^T + (b_ih+b_hh)
  hipLaunchKernelGGL((kGemm<0, 0>), dim3(16, 16), dim3(256), 0, stream,
                     embg, Wihb, biassum, Gpre, (u16*)nullptr, 2048, 256);
  // LSTM recurrence: one cooperative kernel, XCD-local batch partition, per-XCD barriers.
  {
    float* hx = out + 65536000L;             // final h
    float* cx = out + 65536000L + 16384L;    // final c
    const float* gpreA = Gpre; const float* whhA = Whh;
    const float* h0A = h0;     const float* c0A = c0;
    float* hallA = Hall;       int* syncA = syncp;
    void* args[] = {(void*)&gpreA, (void*)&whhA, (void*)&h0A, (void*)&c0A,
                    (void*)&hallA, (void*)&hx, (void*)&cx, (void*)&syncA};
    hipLaunchCooperativeKernel((void*)kLSTM2, dim3(256), dim3(256), args, 0, stream);
  }
  hipLaunchKernelGGL(kAttn, dim3(256), dim3(256), 0, stream, Hall, enc, CAT);
  // OUT[m][512] = tanh(CAT @ attnW^T + attn_b), bf16
  hipLaunchKernelGGL((kGemm<1, 1>), dim3(16, 4), dim3(256), 0, stream,
                     CAT, attnWb, attnb, (float*)nullptr, OUTb, 512, 1024);
  // logits[m][32000] = OUT @ fcW^T + fc_b  (m = b*64+t => contiguous [B,T,V] output)
  hipLaunchKernelGGL((kGemm<0, 0>), dim3(16, 250), dim3(256), 0, stream,
                     OUTb, fcWb, fcb, out, (u16*)nullptr, 32000, 512);
}

// Round 4
// 937.930 us; speedup vs baseline: 2.7336x; 1.0952x over previous
//
#include <hip/hip_runtime.h>
#include <cstdint>
#include <cstddef>

typedef unsigned short u16;
typedef short s8v __attribute__((ext_vector_type(8)));
typedef float f4v __attribute__((ext_vector_type(4)));

static __device__ __forceinline__ u16 f2bf(float x) {
  union { float f; uint32_t u; } v; v.f = x;
  uint32_t r = v.u + 0x7fffu + ((v.u >> 16) & 1u);   // RNE
  return (u16)(r >> 16);
}
static __device__ __forceinline__ float sigm(float x) { return 1.0f / (1.0f + __expf(-x)); }

// ---------------- prep: bf16 conversions + emb gather + bias sum + sync-zero ----------------
__global__ void kPrep(const float* __restrict__ fcW, const float* __restrict__ attnW,
                      const float* __restrict__ Wih, const float* __restrict__ bih,
                      const float* __restrict__ bhh, const float* __restrict__ embW,
                      const int* __restrict__ decX,
                      u16* __restrict__ fcWb, u16* __restrict__ attnWb, u16* __restrict__ Wihb,
                      u16* __restrict__ embg, float* __restrict__ biassum,
                      int* __restrict__ syncp) {
  const long NF = 16384000L, NA = 524288L, NW = 524288L, NE = 524288L, NB = 2048L, NS = 1024L;
  const long total = NF + NA + NW + NE + NB + NS;
  for (long i = (long)blockIdx.x * blockDim.x + threadIdx.x; i < total;
       i += (long)gridDim.x * blockDim.x) {
    if (i < NF) {
      fcWb[i] = f2bf(fcW[i]);
    } else if (i < NF + NA) {
      long k = i - NF; attnWb[k] = f2bf(attnW[k]);
    } else if (i < NF + NA + NW) {
      long k = i - NF - NA; Wihb[k] = f2bf(Wih[k]);
    } else if (i < NF + NA + NW + NE) {
      long k = i - NF - NA - NW;
      int row = (int)(k >> 8), e = (int)(k & 255);   // row = t*32+b
      int t = row >> 5, b = row & 31;
      int x = decX[b * 64 + t];
      embg[k] = f2bf(embW[(long)x * 256 + e]);       // emb_W[0] is all-zero => padding ok
    } else if (i < NF + NA + NW + NE + NB) {
      long k = i - NF - NA - NW - NE;
      biassum[k] = bih[k] + bhh[k];
    } else {
      long k = i - NF - NA - NW - NE - NB;
      syncp[k] = 0;                                  // barrier/enroll counters (ws is poisoned)
    }
  }
}

// ---------------- templated bf16 MFMA GEMM: C[M,N] = A[M,K] * B[N,K]^T + bias ----------------
template <int ACT, int OUTBF>
__global__ __launch_bounds__(256) void kGemm(const u16* __restrict__ A, const u16* __restrict__ Bm,
                                             const float* __restrict__ bias,
                                             float* __restrict__ Cf, u16* __restrict__ Cb,
                                             int N, int K) {
  __shared__ u16 lA[8 * 64 * 8];
  __shared__ u16 lB[8 * 64 * 8];
  const int tid = threadIdx.x;
  const int m0 = blockIdx.x * 128, n0 = blockIdx.y * 128;
  const int lane = tid & 63, wid = tid >> 6;
  const int wm = wid >> 1, wn = wid & 1;
  f4v acc[4][4] = {};
  const int nkt = K >> 5;
  for (int kt = 0; kt < nkt; ++kt) {
    const int k0 = kt << 5;
#pragma unroll
    for (int i = 0; i < 2; ++i) {
      int u = i * 256 + tid;
      int m = u >> 2, q = u & 3;
      uint4 va = *(const uint4*)(A + (size_t)(m0 + m) * K + k0 + q * 8);
      *(uint4*)&lA[(((m >> 4) * 64) + q * 16 + (m & 15)) * 8] = va;
      uint4 vb = *(const uint4*)(Bm + (size_t)(n0 + m) * K + k0 + q * 8);
      *(uint4*)&lB[(((m >> 4) * 64) + q * 16 + (m & 15)) * 8] = vb;
    }
    __syncthreads();
    s8v af[4], bfr[4];
#pragma unroll
    for (int i = 0; i < 4; ++i) af[i] = *(const s8v*)&lA[((wm * 4 + i) * 64 + lane) * 8];
#pragma unroll
    for (int j = 0; j < 4; ++j) bfr[j] = *(const s8v*)&lB[((wn * 4 + j) * 64 + lane) * 8];
#pragma unroll
    for (int i = 0; i < 4; ++i)
#pragma unroll
      for (int j = 0; j < 4; ++j)
        acc[i][j] = __builtin_amdgcn_mfma_f32_16x16x32_bf16(af[i], bfr[j], acc[i][j], 0, 0, 0);
    __syncthreads();
  }
  const int rq = lane >> 4, cl = lane & 15;
#pragma unroll
  for (int j = 0; j < 4; ++j) {
    int col = n0 + wn * 64 + j * 16 + cl;
    float bv = bias[col];
#pragma unroll
    for (int i = 0; i < 4; ++i) {
      int rowb = m0 + wm * 64 + i * 16 + rq * 4;
      f4v v = acc[i][j];
#pragma unroll
      for (int r = 0; r < 4; ++r) {
        float x = v[r] + bv;
        if (ACT) x = tanhf(x);
        size_t off = (size_t)(rowb + r) * N + col;
        if (OUTBF) Cb[off] = f2bf(x); else Cf[off] = x;
      }
    }
  }
}

// ---------------- XCD-local persistent LSTM, Whh in REGISTERS ----------------
// 256 cooperative blocks x 256 threads; 82.5KB static LDS => 1 block/CU (pigeonhole) =>
// exactly 32 blocks/XCD. XCD x owns batches b0=4x..4x+3 (recurrence never leaves its L2).
// Block rank owns 16 h-cols j0=rank*16 (64 Whh rows). W lives in VGPRs for all 64 steps:
// thread (jj=tid>>4, ks=tid&15) holds W[4 gates][8 float4] at k4 = ks+16*i (128 VGPR).
// Per step: stage 8KB h into LDS; 32 broadcast ds_read_b128 (2-way alias = free);
// 512 FMA into 16 partials [g*4+bb]; 15-shfl fold over ks-lanes lands partial p=ks on
// lane ks => (g=ks>>2, bb=ks&3) epilogue identical to the proven R3 layout.
// Per-XCD barrier: monotonic counter in ws, arrive(relaxed)+spin(acquire), L2-local.
__global__ __launch_bounds__(256, 1) void kLSTM3(const float* __restrict__ Gpre,
                                                 const float* __restrict__ Whh,
                                                 const float* __restrict__ h0,
                                                 const float* __restrict__ c0,
                                                 float* __restrict__ Hall,
                                                 float* __restrict__ hx,
                                                 float* __restrict__ cx,
                                                 int* __restrict__ syncp) {
  __shared__ float4 hl4[5160];       // 82,560 B: h stage uses [0..511]; size forces 1 blk/CU
  __shared__ int srank;
  const int tid = threadIdx.x;

  int xcc;
  asm volatile("s_getreg_b32 %0, hwreg(HW_REG_XCC_ID)" : "=s"(xcc));
  xcc &= 7;
  if (tid == 0) srank = atomicAdd(&syncp[xcc * 64], 1);   // enroll: rank within XCD
  __syncthreads();
  const int rank = srank & 31;
  const int j0 = rank * 16;          // 16 h-columns owned by this block
  const int b0 = xcc * 4;            // 4 batches owned by this XCD
  int* cnt = &syncp[(8 + xcc) * 64]; // per-XCD barrier counter (own 256B line)

  const int jj = tid >> 4;           // 0..15: column within block
  const int ks = tid & 15;           // K-slice during compute; (g,bb) after the fold
  const int g_o = ks >> 2, bb_o = ks & 3;
  const int b_o = b0 + bb_o;
  const int j_o = j0 + jj;
  const bool cellLane = (g_o == 0);

  // Whh slice -> registers, once. W[g][i] = Whh[g*512 + j0 + jj][(ks+16i)*4 .. +3]
  const float4* W4 = (const float4*)Whh;   // row stride 128 float4
  float4 Wr[4][8];
#pragma unroll
  for (int g = 0; g < 4; ++g) {
    const int row = g * 512 + j0 + jj;
#pragma unroll
    for (int i = 0; i < 8; ++i) Wr[g][i] = W4[(size_t)row * 128 + ks + 16 * i];
  }

  float creg = cellLane ? c0[b_o * 512 + j_o] : 0.f;
  const float4* hsrc = (const float4*)h0;

  for (int t = 0; t < 64; ++t) {
    // gate-pre from x@Wih^T (+bias), independent of h -> issue early
    float gpv = Gpre[((size_t)t * 32 + b_o) * 2048 + (size_t)g_o * 512 + j_o];

    // stage h_{t-1} for our 4 batches (8KB) into LDS
#pragma unroll
    for (int it = 0; it < 2; ++it) {
      int idx = it * 256 + tid;      // 0..511 float4 chunks
      int hb = idx >> 7, k4 = idx & 127;
      hl4[idx] = hsrc[(b0 + hb) * 128 + k4];
    }
    __syncthreads();

    // 512 FMA into 16 partials; h via 32 broadcast ds_read_b128
    float acc[16];
#pragma unroll
    for (int p = 0; p < 16; ++p) acc[p] = 0.f;
#pragma unroll
    for (int i = 0; i < 8; ++i) {
      float4 h4[4];
#pragma unroll
      for (int bb = 0; bb < 4; ++bb) h4[bb] = hl4[bb * 128 + ks + 16 * i];
#pragma unroll
      for (int g = 0; g < 4; ++g) {
        float4 w = Wr[g][i];
#pragma unroll
        for (int bb = 0; bb < 4; ++bb)
          acc[g * 4 + bb] += w.x * h4[bb].x + w.y * h4[bb].y + w.z * h4[bb].z + w.w * h4[bb].w;
      }
    }

    // fold-reduce 16 partials across the 16 ks-lanes: lane ks ends with total for p=ks
#define FOLD_STAGE(OFF, NN)                                        \
    {                                                              \
      const bool hi = (ks & OFF) != 0;                             \
      _Pragma("unroll")                                            \
      for (int q = 0; q < NN; ++q) {                               \
        float keepv = hi ? acc[q + NN] : acc[q];                   \
        float sendv = hi ? acc[q] : acc[q + NN];                   \
        acc[q] = keepv + __shfl_xor(sendv, OFF, 64);               \
      }                                                            \
    }
    FOLD_STAGE(8, 8)
    FOLD_STAGE(4, 4)
    FOLD_STAGE(2, 2)
    FOLD_STAGE(1, 1)
#undef FOLD_STAGE

    float pre = acc[0] + gpv;
    // activations: one per lane (g lives in lane bits 2..3), gather f,g,o into i-lanes
    float v = (g_o == 2) ? tanhf(pre) : sigm(pre);
    float fv = __shfl_xor(v, 4, 64);
    float gv = __shfl_xor(v, 8, 64);
    float ov = __shfl_xor(v, 12, 64);
    float* hdst = Hall + (size_t)t * 16384;
    if (cellLane) {
      creg = fv * creg + v * gv;               // v = i-gate
      float hv = ov * tanhf(creg);
      hdst[b_o * 512 + j_o] = hv;
      if (t == 63) { hx[b_o * 512 + j_o] = hv; cx[b_o * 512 + j_o] = creg; }
    }
    __syncthreads();                 // drains vmcnt: h stores of ALL waves are in L2

    if (t < 63) {
      if (tid == 0) {
        __hip_atomic_fetch_add(cnt, 1, __ATOMIC_RELAXED, __HIP_MEMORY_SCOPE_AGENT);
        const int target = 32 * (t + 1);
        while (__hip_atomic_load(cnt, __ATOMIC_ACQUIRE, __HIP_MEMORY_SCOPE_AGENT) < target)
          __builtin_amdgcn_s_sleep(1);
      }
      __syncthreads();               // whole block held until XCD barrier passes
    }
    hsrc = (const float4*)hdst;
  }
}

// ---------------- attention: scores -> softmax -> context; emit CAT=[h|c_t] in bf16 ----------
__global__ __launch_bounds__(256) void kAttn(const float* __restrict__ Hall, const float* __restrict__ enc,
                                             u16* __restrict__ CAT) {
  const int bx = blockIdx.x;
  const int b = bx >> 3, tg = bx & 7;     // 8 timesteps per block
  const int tid = threadIdx.x;
  __shared__ float sh[8][516];
  __shared__ float sa[8][132];
  __shared__ float red[8][32];
  for (int tt = 0; tt < 8; ++tt) {
    int t = tg * 8 + tt;
    const float* hr = Hall + ((size_t)t * 32 + b) * 512;
    u16* cr = CAT + ((size_t)(b * 64 + t)) * 1024;
    for (int k = tid; k < 512; k += 256) { float v = hr[k]; sh[tt][k] = v; cr[k] = f2bf(v); }
  }
  __syncthreads();
  {  // scores: thread = (t_local = tid&7, e_base = tid>>3)
    const int tl = tid & 7, eb = tid >> 3;
#pragma unroll
    for (int u = 0; u < 4; ++u) {
      int e = eb + u * 32;
      const float* er = enc + ((size_t)b * 128 + e) * 512;
      float a = 0.f;
      for (int k = 0; k < 512; k += 4) {
        float4 ev = *(const float4*)&er[k];
        float4 hv = *(const float4*)&sh[tl][k];
        a += ev.x * hv.x + ev.y * hv.y + ev.z * hv.z + ev.w * hv.w;
      }
      sa[tl][e] = a;
    }
  }
  __syncthreads();
  {  // softmax over 128 per t
    const int g = tid >> 5, l = tid & 31;
    float mx = -1e30f;
#pragma unroll
    for (int u = 0; u < 4; ++u) mx = fmaxf(mx, sa[g][l + u * 32]);
    red[g][l] = mx;
    __syncthreads();
    if (l == 0) {
      float m2 = -1e30f;
      for (int i = 0; i < 32; ++i) m2 = fmaxf(m2, red[g][i]);
      sa[g][128] = m2;
    }
    __syncthreads();
    float m2 = sa[g][128];
    float s = 0.f;
#pragma unroll
    for (int u = 0; u < 4; ++u) { int e = l + u * 32; float p = __expf(sa[g][e] - m2); sa[g][e] = p; s += p; }
    red[g][l] = s;
    __syncthreads();
    if (l == 0) {
      float s2 = 0.f;
      for (int i = 0; i < 32; ++i) s2 += red[g][i];
      sa[g][129] = 1.0f / s2;
    }
    __syncthreads();
    float inv = sa[g][129];
#pragma unroll
    for (int u = 0; u < 4; ++u) sa[g][l + u * 32] *= inv;
  }
  __syncthreads();
  {  // context: thread covers cols 2*tid, 2*tid+1 for all 8 t
    float a0[8], a1[8];
#pragma unroll
    for (int tt = 0; tt < 8; ++tt) { a0[tt] = 0.f; a1[tt] = 0.f; }
    const float* eb2 = enc + (size_t)b * 128 * 512 + tid * 2;
    for (int e = 0; e < 128; ++e) {
      float2 v = *(const float2*)&eb2[(size_t)e * 512];
#pragma unroll
      for (int tt = 0; tt < 8; ++tt) { float a = sa[tt][e]; a0[tt] += a * v.x; a1[tt] += a * v.y; }
    }
#pragma unroll
    for (int tt = 0; tt < 8; ++tt) {
      int t = tg * 8 + tt;
      u16* cr = CAT + ((size_t)(b * 64 + t)) * 1024 + 512;
      cr[tid * 2] = f2bf(a0[tt]); cr[tid * 2 + 1] = f2bf(a1[tt]);
    }
  }
}

// ---------------- launcher ----------------
extern "C" void kernel_launch(void* const* d_in, const int* in_sizes, int n_in,
                              void* d_out, int out_size, void* d_ws, size_t ws_size,
                              hipStream_t stream) {
  const int*   decX  = (const int*)d_in[0];
  const float* enc   = (const float*)d_in[1];
  const float* h0    = (const float*)d_in[2];
  const float* c0    = (const float*)d_in[3];
  const float* embW  = (const float*)d_in[4];
  const float* Wih   = (const float*)d_in[5];
  const float* Whh   = (const float*)d_in[6];
  const float* bih   = (const float*)d_in[7];
  const float* bhh   = (const float*)d_in[8];
  const float* attnW = (const float*)d_in[9];
  const float* attnb = (const float*)d_in[10];
  const float* fcW   = (const float*)d_in[11];
  const float* fcb   = (const float*)d_in[12];
  float* out = (float*)d_out;

  char* ws = (char*)d_ws;
  u16*   fcWb    = (u16*)(ws);                    // 32,768,000 B
  u16*   attnWb  = (u16*)(ws + 32768000);         //  1,048,576 B
  u16*   Wihb    = (u16*)(ws + 33816576);         //  1,048,576 B
  u16*   embg    = (u16*)(ws + 34865152);         //  1,048,576 B
  float* biassum = (float*)(ws + 35913728);       //      8,192 B
  float* Gpre    = (float*)(ws + 35921920);       // 16,777,216 B
  float* Hall    = (float*)(ws + 52699136);       //  4,194,304 B
  u16*   CAT     = (u16*)(ws + 56893440);         //  4,194,304 B
  u16*   OUTb    = (u16*)(ws + 61087744);         //  2,097,152 B
  int*   syncp   = (int*)(ws + 63184896);         //      4,096 B  (total ~63.2 MB)

  hipLaunchKernelGGL(kPrep, dim3(4096), dim3(256), 0, stream,
                     fcW, attnW, Wih, bih, bhh, embW, decX, fcWb, attnWb, Wihb, embg, biassum,
                     syncp);
  // G_pre[t*32+b][2048] = embg @ Wih^T + (b_ih+b_hh)
  hipLaunchKernelGGL((kGemm<0, 0>), dim3(16, 16), dim3(256), 0, stream,
                     embg, Wihb, biassum, Gpre, (u16*)nullptr, 2048, 256);
  // LSTM recurrence: one cooperative kernel, XCD-local batch partition, per-XCD barriers.
  {
    float* hx = out + 65536000L;             // final h
    float* cx = out + 65536000L + 16384L;    // final c
    const float* gpreA = Gpre; const float* whhA = Whh;
    const float* h0A = h0;     const float* c0A = c0;
    float* hallA = Hall;       int* syncA = syncp;
    void* args[] = {(void*)&gpreA, (void*)&whhA, (void*)&h0A, (void*)&c0A,
                    (void*)&hallA, (void*)&hx, (void*)&cx, (void*)&syncA};
    hipLaunchCooperativeKernel((void*)kLSTM3, dim3(256), dim3(256), args, 0, stream);
  }
  hipLaunchKernelGGL(kAttn, dim3(256), dim3(256), 0, stream, Hall, enc, CAT);
  // OUT[m][512] = tanh(CAT @ attnW^T + attn_b), bf16
  hipLaunchKernelGGL((kGemm<1, 1>), dim3(16, 4), dim3(256), 0, stream,
                     CAT, attnWb, attnb, (float*)nullptr, OUTb, 512, 1024);
  // logits[m][32000] = OUT @ fcW^T + fc_b  (m = b*64+t => contiguous [B,T,V] output)
  hipLaunchKernelGGL((kGemm<0, 0>), dim3(16, 250), dim3(256), 0, stream,
                     OUTb, fcWb, fcb, out, (u16*)nullptr, 32000, 512);
}

// Round 5
// 830.782 us; speedup vs baseline: 3.0862x; 1.1290x over previous
//
#include <hip/hip_runtime.h>
#include <cstdint>
#include <cstddef>

typedef unsigned short u16;
typedef short s8v __attribute__((ext_vector_type(8)));
typedef float f4v __attribute__((ext_vector_type(4)));

static __device__ __forceinline__ u16 f2bf(float x) {
  union { float f; uint32_t u; } v; v.f = x;
  uint32_t r = v.u + 0x7fffu + ((v.u >> 16) & 1u);   // RNE
  return (u16)(r >> 16);
}
static __device__ __forceinline__ float sigm(float x) { return 1.0f / (1.0f + __expf(-x)); }

// ---------------- prep: bf16 conversions + emb gather + bias sum + sync-zero ----------------
__global__ void kPrep(const float* __restrict__ fcW, const float* __restrict__ attnW,
                      const float* __restrict__ Wih, const float* __restrict__ bih,
                      const float* __restrict__ bhh, const float* __restrict__ embW,
                      const int* __restrict__ decX,
                      u16* __restrict__ fcWb, u16* __restrict__ attnWb, u16* __restrict__ Wihb,
                      u16* __restrict__ embg, float* __restrict__ biassum,
                      int* __restrict__ syncp) {
  const long NF = 16384000L, NA = 524288L, NW = 524288L, NE = 524288L, NB = 2048L, NS = 1024L;
  const long total = NF + NA + NW + NE + NB + NS;
  for (long i = (long)blockIdx.x * blockDim.x + threadIdx.x; i < total;
       i += (long)gridDim.x * blockDim.x) {
    if (i < NF) {
      fcWb[i] = f2bf(fcW[i]);
    } else if (i < NF + NA) {
      long k = i - NF; attnWb[k] = f2bf(attnW[k]);
    } else if (i < NF + NA + NW) {
      long k = i - NF - NA; Wihb[k] = f2bf(Wih[k]);
    } else if (i < NF + NA + NW + NE) {
      long k = i - NF - NA - NW;
      int row = (int)(k >> 8), e = (int)(k & 255);   // row = t*32+b
      int t = row >> 5, b = row & 31;
      int x = decX[b * 64 + t];
      embg[k] = f2bf(embW[(long)x * 256 + e]);       // emb_W[0] is all-zero => padding ok
    } else if (i < NF + NA + NW + NE + NB) {
      long k = i - NF - NA - NW - NE;
      biassum[k] = bih[k] + bhh[k];
    } else {
      long k = i - NF - NA - NW - NE - NB;
      syncp[k] = 0;                                  // barrier/enroll counters (ws is poisoned)
    }
  }
}

// ---------------- templated bf16 MFMA GEMM: C[M,N] = A[M,K] * B[N,K]^T + bias ----------------
template <int ACT, int OUTBF>
__global__ __launch_bounds__(256) void kGemm(const u16* __restrict__ A, const u16* __restrict__ Bm,
                                             const float* __restrict__ bias,
                                             float* __restrict__ Cf, u16* __restrict__ Cb,
                                             int N, int K) {
  __shared__ u16 lA[8 * 64 * 8];
  __shared__ u16 lB[8 * 64 * 8];
  const int tid = threadIdx.x;
  const int m0 = blockIdx.x * 128, n0 = blockIdx.y * 128;
  const int lane = tid & 63, wid = tid >> 6;
  const int wm = wid >> 1, wn = wid & 1;
  f4v acc[4][4] = {};
  const int nkt = K >> 5;
  for (int kt = 0; kt < nkt; ++kt) {
    const int k0 = kt << 5;
#pragma unroll
    for (int i = 0; i < 2; ++i) {
      int u = i * 256 + tid;
      int m = u >> 2, q = u & 3;
      uint4 va = *(const uint4*)(A + (size_t)(m0 + m) * K + k0 + q * 8);
      *(uint4*)&lA[(((m >> 4) * 64) + q * 16 + (m & 15)) * 8] = va;
      uint4 vb = *(const uint4*)(Bm + (size_t)(n0 + m) * K + k0 + q * 8);
      *(uint4*)&lB[(((m >> 4) * 64) + q * 16 + (m & 15)) * 8] = vb;
    }
    __syncthreads();
    s8v af[4], bfr[4];
#pragma unroll
    for (int i = 0; i < 4; ++i) af[i] = *(const s8v*)&lA[((wm * 4 + i) * 64 + lane) * 8];
#pragma unroll
    for (int j = 0; j < 4; ++j) bfr[j] = *(const s8v*)&lB[((wn * 4 + j) * 64 + lane) * 8];
#pragma unroll
    for (int i = 0; i < 4; ++i)
#pragma unroll
      for (int j = 0; j < 4; ++j)
        acc[i][j] = __builtin_amdgcn_mfma_f32_16x16x32_bf16(af[i], bfr[j], acc[i][j], 0, 0, 0);
    __syncthreads();
  }
  const int rq = lane >> 4, cl = lane & 15;
#pragma unroll
  for (int j = 0; j < 4; ++j) {
    int col = n0 + wn * 64 + j * 16 + cl;
    float bv = bias[col];
#pragma unroll
    for (int i = 0; i < 4; ++i) {
      int rowb = m0 + wm * 64 + i * 16 + rq * 4;
      f4v v = acc[i][j];
#pragma unroll
      for (int r = 0; r < 4; ++r) {
        float x = v[r] + bv;
        if (ACT) x = tanhf(x);
        size_t off = (size_t)(rowb + r) * N + col;
        if (OUTBF) Cb[off] = f2bf(x); else Cf[off] = x;
      }
    }
  }
}

// ---------------- XCD-local persistent LSTM, Whh in registers, L2-LOCAL barrier ----------------
// 256 cooperative blocks x 256 threads; 82.5KB static LDS => 1 block/CU (pigeonhole) =>
// exactly 32 blocks/XCD. XCD x owns batches b0=4x..4x+3 (recurrence never leaves its L2).
// Block rank owns 16 h-cols j0=rank*16 (64 Whh rows) in VGPRs for all 64 steps.
// Per step: stage 8KB h into LDS; 32 broadcast ds_read_b128; 512 FMA into 16 partials;
// 15-shfl fold lands partial p=ks on lane ks => (g=ks>>2, bb=ks&3) epilogue.
// Barrier: hand-rolled global_atomic_add WITHOUT sc1 => executes in the XCD's OWN L2
// (the intra-XCD coherence point; all participants are same-XCD by construction).
// Poll = atomic-add-0 sc0 (returns current value; always L2, never stale L1).
// Gpre(t+1) is prefetched during step t's compute to hide its L3 latency.
__global__ __launch_bounds__(256, 1) void kLSTM4(const float* __restrict__ Gpre,
                                                 const float* __restrict__ Whh,
                                                 const float* __restrict__ h0,
                                                 const float* __restrict__ c0,
                                                 float* __restrict__ Hall,
                                                 float* __restrict__ hx,
                                                 float* __restrict__ cx,
                                                 int* __restrict__ syncp) {
  __shared__ float4 hl4[5160];       // 82,560 B: h stage uses [0..511]; size forces 1 blk/CU
  __shared__ int srank;
  const int tid = threadIdx.x;

  int xcc;
  asm volatile("s_getreg_b32 %0, hwreg(HW_REG_XCC_ID)" : "=s"(xcc));
  xcc &= 7;
  if (tid == 0) srank = atomicAdd(&syncp[xcc * 64], 1);   // enroll (device scope, once)
  __syncthreads();
  const int rank = srank & 31;
  const int j0 = rank * 16;          // 16 h-columns owned by this block
  const int b0 = xcc * 4;            // 4 batches owned by this XCD
  int* cnt = &syncp[(8 + xcc) * 64]; // per-XCD barrier counter (own 256B line; only this
                                     // XCD ever touches it with L2-local atomics)

  const int jj = tid >> 4;           // 0..15: column within block
  const int ks = tid & 15;           // K-slice during compute; (g,bb) after the fold
  const int g_o = ks >> 2, bb_o = ks & 3;
  const int b_o = b0 + bb_o;
  const int j_o = j0 + jj;
  const bool cellLane = (g_o == 0);

  // Whh slice -> registers, once. W[g][i] = Whh[g*512 + j0 + jj][(ks+16i)*4 .. +3]
  const float4* W4 = (const float4*)Whh;   // row stride 128 float4
  float4 Wr[4][8];
#pragma unroll
  for (int g = 0; g < 4; ++g) {
    const int row = g * 512 + j0 + jj;
#pragma unroll
    for (int i = 0; i < 8; ++i) Wr[g][i] = W4[(size_t)row * 128 + ks + 16 * i];
  }

  float creg = cellLane ? c0[b_o * 512 + j_o] : 0.f;
  const float4* hsrc = (const float4*)h0;
  // prefetch t=0 gate-pre
  float gpv = Gpre[(size_t)b_o * 2048 + (size_t)g_o * 512 + j_o];

  for (int t = 0; t < 64; ++t) {
    // stage h_{t-1} for our 4 batches (8KB) into LDS
#pragma unroll
    for (int it = 0; it < 2; ++it) {
      int idx = it * 256 + tid;      // 0..511 float4 chunks
      int hb = idx >> 7, k4 = idx & 127;
      hl4[idx] = hsrc[(b0 + hb) * 128 + k4];
    }
    __syncthreads();

    // prefetch next step's gate-pre (consumed after the next barrier -> latency hidden)
    float gnext = 0.f;
    if (t < 63)
      gnext = Gpre[((size_t)(t + 1) * 32 + b_o) * 2048 + (size_t)g_o * 512 + j_o];

    // 512 FMA into 16 partials; h via 32 broadcast ds_read_b128
    float acc[16];
#pragma unroll
    for (int p = 0; p < 16; ++p) acc[p] = 0.f;
#pragma unroll
    for (int i = 0; i < 8; ++i) {
      float4 h4[4];
#pragma unroll
      for (int bb = 0; bb < 4; ++bb) h4[bb] = hl4[bb * 128 + ks + 16 * i];
#pragma unroll
      for (int g = 0; g < 4; ++g) {
        float4 w = Wr[g][i];
#pragma unroll
        for (int bb = 0; bb < 4; ++bb)
          acc[g * 4 + bb] += w.x * h4[bb].x + w.y * h4[bb].y + w.z * h4[bb].z + w.w * h4[bb].w;
      }
    }

    // fold-reduce 16 partials across the 16 ks-lanes: lane ks ends with total for p=ks
#define FOLD_STAGE(OFF, NN)                                        \
    {                                                              \
      const bool hi = (ks & OFF) != 0;                             \
      _Pragma("unroll")                                            \
      for (int q = 0; q < NN; ++q) {                               \
        float keepv = hi ? acc[q + NN] : acc[q];                   \
        float sendv = hi ? acc[q] : acc[q + NN];                   \
        acc[q] = keepv + __shfl_xor(sendv, OFF, 64);               \
      }                                                            \
    }
    FOLD_STAGE(8, 8)
    FOLD_STAGE(4, 4)
    FOLD_STAGE(2, 2)
    FOLD_STAGE(1, 1)
#undef FOLD_STAGE

    float pre = acc[0] + gpv;
    // activations: one per lane (g lives in lane bits 2..3), gather f,g,o into i-lanes
    float v = (g_o == 2) ? tanhf(pre) : sigm(pre);
    float fv = __shfl_xor(v, 4, 64);
    float gv = __shfl_xor(v, 8, 64);
    float ov = __shfl_xor(v, 12, 64);
    float* hdst = Hall + (size_t)t * 16384;
    if (cellLane) {
      creg = fv * creg + v * gv;               // v = i-gate
      float hv = ov * tanhf(creg);
      hdst[b_o * 512 + j_o] = hv;
      if (t == 63) { hx[b_o * 512 + j_o] = hv; cx[b_o * 512 + j_o] = creg; }
    }
    __syncthreads();                 // compiler emits vmcnt(0): all waves' h stores are in L2

    if (t < 63) {
      if (tid == 0) {
        // arrive: L2-local atomic (no sc1 => executes at this XCD's L2)
        unsigned one = 1u;
        asm volatile("global_atomic_add %0, %1, off"
                     :: "v"(cnt), "v"(one) : "memory");
        const int target = 32 * (t + 1);
        unsigned zero = 0u, old;
        for (;;) {
          // poll: atomic-add-0 with sc0 (returns pre-value; L2-resident, never stale L1)
          asm volatile("global_atomic_add %0, %1, %2, off sc0\n\t"
                       "s_waitcnt vmcnt(0)"
                       : "=v"(old) : "v"(cnt), "v"(zero) : "memory");
          if ((int)old >= target) break;
          __builtin_amdgcn_s_sleep(1);
        }
      }
      __syncthreads();               // whole block held until XCD barrier passes
    }
    gpv = gnext;
    hsrc = (const float4*)hdst;
  }
}

// ---------------- attention: scores -> softmax -> context; emit CAT=[h|c_t] in bf16 ----------
__global__ __launch_bounds__(256) void kAttn(const float* __restrict__ Hall, const float* __restrict__ enc,
                                             u16* __restrict__ CAT) {
  const int bx = blockIdx.x;
  const int b = bx >> 3, tg = bx & 7;     // 8 timesteps per block
  const int tid = threadIdx.x;
  __shared__ float sh[8][516];
  __shared__ float sa[8][132];
  __shared__ float red[8][32];
  for (int tt = 0; tt < 8; ++tt) {
    int t = tg * 8 + tt;
    const float* hr = Hall + ((size_t)t * 32 + b) * 512;
    u16* cr = CAT + ((size_t)(b * 64 + t)) * 1024;
    for (int k = tid; k < 512; k += 256) { float v = hr[k]; sh[tt][k] = v; cr[k] = f2bf(v); }
  }
  __syncthreads();
  {  // scores: thread = (t_local = tid&7, e_base = tid>>3)
    const int tl = tid & 7, eb = tid >> 3;
#pragma unroll
    for (int u = 0; u < 4; ++u) {
      int e = eb + u * 32;
      const float* er = enc + ((size_t)b * 128 + e) * 512;
      float a = 0.f;
      for (int k = 0; k < 512; k += 4) {
        float4 ev = *(const float4*)&er[k];
        float4 hv = *(const float4*)&sh[tl][k];
        a += ev.x * hv.x + ev.y * hv.y + ev.z * hv.z + ev.w * hv.w;
      }
      sa[tl][e] = a;
    }
  }
  __syncthreads();
  {  // softmax over 128 per t
    const int g = tid >> 5, l = tid & 31;
    float mx = -1e30f;
#pragma unroll
    for (int u = 0; u < 4; ++u) mx = fmaxf(mx, sa[g][l + u * 32]);
    red[g][l] = mx;
    __syncthreads();
    if (l == 0) {
      float m2 = -1e30f;
      for (int i = 0; i < 32; ++i) m2 = fmaxf(m2, red[g][i]);
      sa[g][128] = m2;
    }
    __syncthreads();
    float m2 = sa[g][128];
    float s = 0.f;
#pragma unroll
    for (int u = 0; u < 4; ++u) { int e = l + u * 32; float p = __expf(sa[g][e] - m2); sa[g][e] = p; s += p; }
    red[g][l] = s;
    __syncthreads();
    if (l == 0) {
      float s2 = 0.f;
      for (int i = 0; i < 32; ++i) s2 += red[g][i];
      sa[g][129] = 1.0f / s2;
    }
    __syncthreads();
    float inv = sa[g][129];
#pragma unroll
    for (int u = 0; u < 4; ++u) sa[g][l + u * 32] *= inv;
  }
  __syncthreads();
  {  // context: thread covers cols 2*tid, 2*tid+1 for all 8 t
    float a0[8], a1[8];
#pragma unroll
    for (int tt = 0; tt < 8; ++tt) { a0[tt] = 0.f; a1[tt] = 0.f; }
    const float* eb2 = enc + (size_t)b * 128 * 512 + tid * 2;
    for (int e = 0; e < 128; ++e) {
      float2 v = *(const float2*)&eb2[(size_t)e * 512];
#pragma unroll
      for (int tt = 0; tt < 8; ++tt) { float a = sa[tt][e]; a0[tt] += a * v.x; a1[tt] += a * v.y; }
    }
#pragma unroll
    for (int tt = 0; tt < 8; ++tt) {
      int t = tg * 8 + tt;
      u16* cr = CAT + ((size_t)(b * 64 + t)) * 1024 + 512;
      cr[tid * 2] = f2bf(a0[tt]); cr[tid * 2 + 1] = f2bf(a1[tt]);
    }
  }
}

// ---------------- launcher ----------------
extern "C" void kernel_launch(void* const* d_in, const int* in_sizes, int n_in,
                              void* d_out, int out_size, void* d_ws, size_t ws_size,
                              hipStream_t stream) {
  const int*   decX  = (const int*)d_in[0];
  const float* enc   = (const float*)d_in[1];
  const float* h0    = (const float*)d_in[2];
  const float* c0    = (const float*)d_in[3];
  const float* embW  = (const float*)d_in[4];
  const float* Wih   = (const float*)d_in[5];
  const float* Whh   = (const float*)d_in[6];
  const float* bih   = (const float*)d_in[7];
  const float* bhh   = (const float*)d_in[8];
  const float* attnW = (const float*)d_in[9];
  const float* attnb = (const float*)d_in[10];
  const float* fcW   = (const float*)d_in[11];
  const float* fcb   = (const float*)d_in[12];
  float* out = (float*)d_out;

  char* ws = (char*)d_ws;
  u16*   fcWb    = (u16*)(ws);                    // 32,768,000 B
  u16*   attnWb  = (u16*)(ws + 32768000);         //  1,048,576 B
  u16*   Wihb    = (u16*)(ws + 33816576);         //  1,048,576 B
  u16*   embg    = (u16*)(ws + 34865152);         //  1,048,576 B
  float* biassum = (float*)(ws + 35913728);       //      8,192 B
  float* Gpre    = (float*)(ws + 35921920);       // 16,777,216 B
  float* Hall    = (float*)(ws + 52699136);       //  4,194,304 B
  u16*   CAT     = (u16*)(ws + 56893440);         //  4,194,304 B
  u16*   OUTb    = (u16*)(ws + 61087744);         //  2,097,152 B
  int*   syncp   = (int*)(ws + 63184896);         //      4,096 B  (total ~63.2 MB)

  hipLaunchKernelGGL(kPrep, dim3(4096), dim3(256), 0, stream,
                     fcW, attnW, Wih, bih, bhh, embW, decX, fcWb, attnWb, Wihb, embg, biassum,
                     syncp);
  // G_pre[t*32+b][2048] = embg @ Wih^T + (b_ih+b_hh)
  hipLaunchKernelGGL((kGemm<0, 0>), dim3(16, 16), dim3(256), 0, stream,
                     embg, Wihb, biassum, Gpre, (u16*)nullptr, 2048, 256);
  // LSTM recurrence: one cooperative kernel, XCD-local batch partition, L2-local barriers.
  {
    float* hx = out + 65536000L;             // final h
    float* cx = out + 65536000L + 16384L;    // final c
    const float* gpreA = Gpre; const float* whhA = Whh;
    const float* h0A = h0;     const float* c0A = c0;
    float* hallA = Hall;       int* syncA = syncp;
    void* args[] = {(void*)&gpreA, (void*)&whhA, (void*)&h0A, (void*)&c0A,
                    (void*)&hallA, (void*)&hx, (void*)&cx, (void*)&syncA};
    hipLaunchCooperativeKernel((void*)kLSTM4, dim3(256), dim3(256), args, 0, stream);
  }
  hipLaunchKernelGGL(kAttn, dim3(256), dim3(256), 0, stream, Hall, enc, CAT);
  // OUT[m][512] = tanh(CAT @ attnW^T + attn_b), bf16
  hipLaunchKernelGGL((kGemm<1, 1>), dim3(16, 4), dim3(256), 0, stream,
                     CAT, attnWb, attnb, (float*)nullptr, OUTb, 512, 1024);
  // logits[m][32000] = OUT @ fcW^T + fc_b  (m = b*64+t => contiguous [B,T,V] output)
  hipLaunchKernelGGL((kGemm<0, 0>), dim3(16, 250), dim3(256), 0, stream,
                     OUTb, fcWb, fcb, out, (u16*)nullptr, 32000, 512);
}